// Round 2
// baseline (399.754 us; speedup 1.0000x reference)
//
#include <hip/hip_runtime.h>
#include <math.h>

#define TOKS  16384
#define HD    4096
#define NE    64
#define MT    32          // tokens per block
#define KT    64          // K tile
#define NTHR  256         // 4 waves
#define NTILE (HD / KT)   // 64

typedef unsigned int   u32;
typedef unsigned short u16;
typedef short v8s __attribute__((ext_vector_type(8)));   // 8 bf16
typedef float v4f __attribute__((ext_vector_type(4)));   // 4 fp32

// exact split: a ≈ hi + lo, both bf16 (truncation); residual ~2^-17 rel
__device__ __forceinline__ void split2(float a, float b, u32& hi, u32& lo) {
    u32 ua = __float_as_uint(a), ub = __float_as_uint(b);
    hi = (ub & 0xffff0000u) | (ua >> 16);
    float la = a - __uint_as_float(ua & 0xffff0000u);
    float lb = b - __uint_as_float(ub & 0xffff0000u);
    lo = (__float_as_uint(lb) & 0xffff0000u) | (__float_as_uint(la) >> 16);
}

// Pre-pass: W [NE][HD] fp32 -> per-K-tile LDS images, 16 KiB per tile:
//   byte addr within tile block = p*8192 + e*128 + ((j*2) ^ ((e&7)<<4))
// XOR swizzle pre-applied so the router can global_load_lds LINEARLY
// (rule 21: swizzled source + linear dest + swizzled read).
__global__ __launch_bounds__(256) void wsplit_kernel(const float* __restrict__ W,
                                                     char* __restrict__ wsd) {
    const int gid = blockIdx.x * 256 + threadIdx.x;   // 65536 threads, one float4 each
    const float4 f = ((const float4*)W)[gid];
    const int idx = gid << 2;
    const int e   = idx >> 12;        // expert row (HD = 4096)
    const int col = idx & 4095;
    const int k   = col >> 6;         // K-tile
    const int j   = col & 63;         // col within tile (multiple of 4)
    u32 h0, h1, l0, l1;
    split2(f.x, f.y, h0, l0);
    split2(f.z, f.w, h1, l1);
    char* base = wsd + ((size_t)k << 14) + (e << 7) + ((j << 1) ^ ((e & 7) << 4));
    *(uint2*)(base)        = make_uint2(h0, h1);   // hi plane
    *(uint2*)(base + 8192) = make_uint2(l0, l1);   // lo plane
}

#define GLDS(G, L)                                                             \
    __builtin_amdgcn_global_load_lds(                                          \
        (const __attribute__((address_space(1))) u32*)(G),                     \
        (__attribute__((address_space(3))) u32*)(L), 16, 0, 0)

// counted-vmcnt barrier discipline (T3/T4): wave waits its OWN tile-t loads
// (vmcnt leaves the 16 newer ops of t+1,t+2 in flight), then raw barrier.
// sched_barrier(0) fences code motion (rule 18).
#define VMW16() asm volatile("s_waitcnt vmcnt(16)" ::: "memory")
#define VMW8()  asm volatile("s_waitcnt vmcnt(8)"  ::: "memory")
#define VMW0()  asm volatile("s_waitcnt vmcnt(0)"  ::: "memory")
#define BARR()  do { __builtin_amdgcn_s_barrier();                             \
                     __builtin_amdgcn_sched_barrier(0); } while (0)

__global__ __launch_bounds__(NTHR, 2) void router_kernel(
    const float* __restrict__ x, const char* __restrict__ wsd,
    float* __restrict__ scores, float* __restrict__ wout, float* __restrict__ iout)
{
    __shared__ __align__(16) u16 WT[4][8192];   // four 16-KiB W tile images (hi|lo)
    __shared__ float Ls[MT][NE + 1];
    __shared__ float Ssum[MT], Smax[MT];

    const int t    = threadIdx.x;
    const int tok0 = blockIdx.x * MT;
    const int lane = t & 63;
    const int w    = t >> 6;          // 0..3
    const int wt   = w & 1;           // token group (16)
    const int weh  = w >> 1;          // expert half (32)
    const int q    = lane >> 4, r = lane & 15;
    const int arow  = wt * 16 + r;
    const int brow0 = weh * 32 + r;
    const int brow1 = weh * 32 + 16 + r;

    // x: direct per-lane fragment loads (A-frag = 8 consecutive floats of one row)
    const float* xrow = x + (size_t)(tok0 + arow) * HD;
    const int qe = q * 8;

    // W: swizzled LDS read offsets (byte): plane + row*128 + (colbyte ^ (row&7)<<4)
    const int sw0 = (brow0 & 7) << 4;
    const int sw1 = (brow1 & 7) << 4;
    const int ob0h = brow0 * 128, ob0l = 8192 + ob0h;
    const int ob1h = brow1 * 128, ob1l = 8192 + ob1h;
    const int q16 = q * 16;
    const int c00 = ob0h + ((q16)      ^ sw0);
    const int c01 = ob0h + ((64 + q16) ^ sw0);
    const int d00 = ob0l + ((q16)      ^ sw0);
    const int d01 = ob0l + ((64 + q16) ^ sw0);
    const int c10 = ob1h + ((q16)      ^ sw1);
    const int c11 = ob1h + ((64 + q16) ^ sw1);
    const int d10 = ob1l + ((q16)      ^ sw1);
    const int d11 = ob1l + ((64 + q16) ^ sw1);

    // per-wave W staging: wave w copies bytes [w*4096, (w+1)*4096) of the image
    const char* wsl = wsd + w * 4096 + lane * 16;
    char* const wtbase = (char*)&WT[0][0];

    v4f acc0 = {0.f, 0.f, 0.f, 0.f};
    v4f acc1 = {0.f, 0.f, 0.f, 0.f};

    float4 a0A, a1A, a2A, a3A, a0B, a1B, a2B, a3B;
    float4 a0C, a1C, a2C, a3C, a0D, a1D, a2D, a3D;

#define XLOAD(S, T)                                                 \
    do { const float* xp = xrow + (T) * KT + qe;                    \
         a0##S = *(const float4*)(xp);                              \
         a1##S = *(const float4*)(xp + 4);                          \
         a2##S = *(const float4*)(xp + 32);                         \
         a3##S = *(const float4*)(xp + 36); } while (0)

#define STAGE_W(T, B)                                               \
    do { const char* gs = wsl + ((size_t)(T) << 14);                \
         char* ls = wtbase + (B) * 16384 + w * 4096;                \
         GLDS(gs,        ls);                                       \
         GLDS(gs + 1024, ls + 1024);                                \
         GLDS(gs + 2048, ls + 2048);                                \
         GLDS(gs + 3072, ls + 3072); } while (0)

#define COMPUTE(S, B)                                                            \
    do {                                                                         \
        const char* WB = wtbase + (B) * 16384;                                   \
        union { v8s v; u32 u[4]; } ah, al;                                       \
        v8s bh0, bl0, bh1, bl1;                                                  \
        /* c = 0 */                                                              \
        split2(a0##S.x, a0##S.y, ah.u[0], al.u[0]);                              \
        split2(a0##S.z, a0##S.w, ah.u[1], al.u[1]);                              \
        split2(a1##S.x, a1##S.y, ah.u[2], al.u[2]);                              \
        split2(a1##S.z, a1##S.w, ah.u[3], al.u[3]);                              \
        bh0 = *(const v8s*)(WB + c00); bl0 = *(const v8s*)(WB + d00);            \
        bh1 = *(const v8s*)(WB + c10); bl1 = *(const v8s*)(WB + d10);            \
        acc0 = __builtin_amdgcn_mfma_f32_16x16x32_bf16(ah.v, bh0, acc0, 0, 0, 0);\
        acc0 = __builtin_amdgcn_mfma_f32_16x16x32_bf16(al.v, bh0, acc0, 0, 0, 0);\
        acc0 = __builtin_amdgcn_mfma_f32_16x16x32_bf16(ah.v, bl0, acc0, 0, 0, 0);\
        acc1 = __builtin_amdgcn_mfma_f32_16x16x32_bf16(ah.v, bh1, acc1, 0, 0, 0);\
        acc1 = __builtin_amdgcn_mfma_f32_16x16x32_bf16(al.v, bh1, acc1, 0, 0, 0);\
        acc1 = __builtin_amdgcn_mfma_f32_16x16x32_bf16(ah.v, bl1, acc1, 0, 0, 0);\
        /* c = 1 */                                                              \
        split2(a2##S.x, a2##S.y, ah.u[0], al.u[0]);                              \
        split2(a2##S.z, a2##S.w, ah.u[1], al.u[1]);                              \
        split2(a3##S.x, a3##S.y, ah.u[2], al.u[2]);                              \
        split2(a3##S.z, a3##S.w, ah.u[3], al.u[3]);                              \
        bh0 = *(const v8s*)(WB + c01); bl0 = *(const v8s*)(WB + d01);            \
        bh1 = *(const v8s*)(WB + c11); bl1 = *(const v8s*)(WB + d11);            \
        acc0 = __builtin_amdgcn_mfma_f32_16x16x32_bf16(ah.v, bh0, acc0, 0, 0, 0);\
        acc0 = __builtin_amdgcn_mfma_f32_16x16x32_bf16(al.v, bh0, acc0, 0, 0, 0);\
        acc0 = __builtin_amdgcn_mfma_f32_16x16x32_bf16(ah.v, bl0, acc0, 0, 0, 0);\
        acc1 = __builtin_amdgcn_mfma_f32_16x16x32_bf16(ah.v, bh1, acc1, 0, 0, 0);\
        acc1 = __builtin_amdgcn_mfma_f32_16x16x32_bf16(al.v, bh1, acc1, 0, 0, 0);\
        acc1 = __builtin_amdgcn_mfma_f32_16x16x32_bf16(ah.v, bl1, acc1, 0, 0, 0);\
    } while (0)

    // prologue: 3 tiles in flight (8 VMEM ops each, GLDS first then x loads)
    STAGE_W(0, 0); XLOAD(A, 0);
    STAGE_W(1, 1); XLOAD(B, 1);
    STAGE_W(2, 2); XLOAD(C, 2);

    // main loop: tiles 0..59, depth-3 pipeline, one raw barrier per tile.
    // staging tile u+3 reuses the buffer last read at tile u-1 (all waves
    // provably past it: their ds_reads were lgkm-consumed before barrier u).
    for (int tt = 0; tt < 60; tt += 4) {
        VMW16(); BARR();
        STAGE_W(tt + 3, 3); XLOAD(D, tt + 3);
        COMPUTE(A, 0);
        VMW16(); BARR();
        STAGE_W(tt + 4, 0); XLOAD(A, tt + 4);
        COMPUTE(B, 1);
        VMW16(); BARR();
        STAGE_W(tt + 5, 1); XLOAD(B, tt + 5);
        COMPUTE(C, 2);
        VMW16(); BARR();
        STAGE_W(tt + 6, 2); XLOAD(C, tt + 6);
        COMPUTE(D, 3);
    }
    // epilogue: tiles 60..63, waits decay as the queue drains
    VMW16(); BARR();
    STAGE_W(63, 3); XLOAD(D, 63);
    COMPUTE(A, 0);
    VMW16(); BARR();
    COMPUTE(B, 1);
    VMW8();  BARR();
    COMPUTE(C, 2);
    VMW0();  BARR();
    COMPUTE(D, 3);

    // scatter logits (D layout: col = lane&15, row = (lane>>4)*4 + reg)
#pragma unroll
    for (int reg = 0; reg < 4; ++reg) {
        Ls[wt * 16 + q * 4 + reg][weh * 32 + r]      = acc0[reg];
        Ls[wt * 16 + q * 4 + reg][weh * 32 + 16 + r] = acc1[reg];
    }
    __syncthreads();

    // parallel softmax + top-2: 8 lanes per token, shuffle-butterfly merge
    {
        const int tk = t >> 3;        // 0..31
        const int sl = t & 7;         // lane within token group
        float m = -3.402823466e+38f;
#pragma unroll
        for (int j = 0; j < 8; ++j) m = fmaxf(m, Ls[tk][sl + 8 * j]);
#pragma unroll
        for (int d = 1; d < 8; d <<= 1) m = fmaxf(m, __shfl_xor(m, d, 64));

        float s = 0.f, v1 = -1.f, v2 = -1.f;
        int   i1 = 0, i2 = 0;
#pragma unroll
        for (int j = 0; j < 8; ++j) {
            const int e = sl + 8 * j;
            const float ex = expf(Ls[tk][e] - m);
            s += ex;
            if (ex > v1)      { v2 = v1; i2 = i1; v1 = ex; i1 = e; }
            else if (ex > v2) { v2 = ex; i2 = e; }
        }
#pragma unroll
        for (int d = 1; d < 8; d <<= 1) {
            const float ov1 = __shfl_xor(v1, d, 64);
            const int   oi1 = __shfl_xor(i1, d, 64);
            const float ov2 = __shfl_xor(v2, d, 64);
            const int   oi2 = __shfl_xor(i2, d, 64);
            s += __shfl_xor(s, d, 64);
            // merge two sorted top-2 sets; ties -> lower index (jax.lax.top_k)
            if (ov1 > v1 || (ov1 == v1 && oi1 < i1)) {
                if (ov2 > v1 || (ov2 == v1 && oi2 < i1)) { v2 = ov2; i2 = oi2; }
                else                                     { v2 = v1;  i2 = i1;  }
                v1 = ov1; i1 = oi1;
            } else if (ov1 > v2 || (ov1 == v2 && oi1 < i2)) {
                v2 = ov1; i2 = oi1;
            }
        }
        if (sl == 0) {
            const float s1 = v1 / s, s2 = v2 / s;
            const float ws_ = s1 + s2;
            wout[(size_t)(tok0 + tk) * 2 + 0] = s1 / ws_;
            wout[(size_t)(tok0 + tk) * 2 + 1] = s2 / ws_;
            iout[(size_t)(tok0 + tk) * 2 + 0] = (float)i1;
            iout[(size_t)(tok0 + tk) * 2 + 1] = (float)i2;
            Ssum[tk] = s;
            Smax[tk] = m;
        }
    }
    __syncthreads();

    // coalesced scores write: 32*64 = 2048 elems / 256 threads
#pragma unroll
    for (int it = 0; it < (MT * NE) / NTHR; ++it) {
        const int f  = it * NTHR + t;
        const int tk = f >> 6, e = f & 63;
        scores[(size_t)(tok0 + tk) * NE + e] = expf(Ls[tk][e] - Smax[tk]) / Ssum[tk];
    }
}

extern "C" void kernel_launch(void* const* d_in, const int* in_sizes, int n_in,
                              void* d_out, int out_size, void* d_ws, size_t ws_size,
                              hipStream_t stream) {
    (void)in_sizes; (void)n_in; (void)out_size; (void)ws_size;
    const float* x = (const float*)d_in[0];
    const float* W = (const float*)d_in[1];
    float* out    = (float*)d_out;
    float* scores = out;
    float* wout   = scores + (size_t)TOKS * NE;
    float* iout   = wout   + (size_t)TOKS * 2;

    char* wsd = (char*)d_ws;   // 64 tiles x 16 KiB = 1 MiB

    wsplit_kernel<<<dim3(256), dim3(256), 0, stream>>>(W, wsd);
    router_kernel<<<dim3(TOKS / MT), dim3(NTHR), 0, stream>>>(x, wsd, scores, wout, iout);
}

// Round 4
// 394.302 us; speedup vs baseline: 1.0138x; 1.0138x over previous
//
#include <hip/hip_runtime.h>
#include <math.h>

#define TOKS  16384
#define HD    4096
#define NE    64
#define MT    32          // tokens per block
#define KT    64          // K tile
#define NTHR  256         // 4 waves
#define LST   72          // LDS row stride in bf16 (64 + 8 pad)
#define NTILE (HD / KT)   // 64

typedef unsigned int   u32;
typedef unsigned short u16;
typedef short v8s __attribute__((ext_vector_type(8)));   // 8 bf16
typedef float v4f __attribute__((ext_vector_type(4)));   // 4 fp32

// exact split: a ≈ hi + lo, both bf16 (truncation); residual ~2^-17 rel
__device__ __forceinline__ void split2(float a, float b, u32& hi, u32& lo) {
    u32 ua = __float_as_uint(a), ub = __float_as_uint(b);
    hi = (ub & 0xffff0000u) | (ua >> 16);
    float la = a - __uint_as_float(ua & 0xffff0000u);
    float lb = b - __uint_as_float(ub & 0xffff0000u);
    lo = (__float_as_uint(lb) & 0xffff0000u) | (__float_as_uint(la) >> 16);
}

// Pre-pass: split W [NE][HD] fp32 -> bf16 hi/lo planes in d_ws
__global__ __launch_bounds__(256) void wsplit_kernel(const float* __restrict__ W,
                                                     u16* __restrict__ wh, u16* __restrict__ wl) {
    const int gid = blockIdx.x * 256 + threadIdx.x;   // 65536 threads, one float4 each
    const float4 f = ((const float4*)W)[gid];
    u32 h0, h1, l0, l1;
    split2(f.x, f.y, h0, l0);
    split2(f.z, f.w, h1, l1);
    u32* whp = (u32*)wh; u32* wlp = (u32*)wl;
    whp[gid * 2 + 0] = h0; whp[gid * 2 + 1] = h1;
    wlp[gid * 2 + 0] = l0; wlp[gid * 2 + 1] = l1;
}

__global__ __launch_bounds__(NTHR, 2) void router_kernel(
    const float* __restrict__ x, const u16* __restrict__ wh, const u16* __restrict__ wl,
    float* __restrict__ scores, float* __restrict__ wout, float* __restrict__ iout)
{
    __shared__ u16 Xh[2][MT][LST], Xl[2][MT][LST];
    __shared__ u16 Wh[2][NE][LST], Wl[2][NE][LST];
    __shared__ float Ls[MT][NE + 1];
    __shared__ float Ssum[MT], Smax[MT];

    const int t    = threadIdx.x;
    const int tok0 = blockIdx.x * MT;
    // X staging: 32 rows x 8 float4-cols
    const int srow = t >> 3, sc = t & 7;
    // W staging: 64 rows x 4 uint4-cols (two segments per row)
    const int wrow = t >> 2, wc = t & 3;
    // compute mapping
    const int lane = t & 63;
    const int w    = t >> 6;          // 0..3
    const int wt   = w & 1;           // token group (16)
    const int weh  = w >> 1;          // expert half (32)
    const int q    = lane >> 4, r = lane & 15;
    const int arow  = wt * 16 + r;
    const int brow0 = weh * 32 + r;
    const int brow1 = weh * 32 + 16 + r;

    v4f acc0 = {0.f, 0.f, 0.f, 0.f};
    v4f acc1 = {0.f, 0.f, 0.f, 0.f};

    const size_t xbase = (size_t)(tok0 + srow) * HD;
    const size_t wbase = (size_t)wrow * HD;

    float4 xr0, xr1;
    uint4  whr0, whr1, wlr0, wlr1;

#define LOAD_TILE(K0)                                               \
    do {                                                            \
        xr0  = *(const float4*)&x[xbase + (K0) + sc * 4];           \
        xr1  = *(const float4*)&x[xbase + (K0) + 32 + sc * 4];      \
        whr0 = *(const uint4*)&wh[wbase + (K0) + wc * 8];           \
        whr1 = *(const uint4*)&wh[wbase + (K0) + 32 + wc * 8];      \
        wlr0 = *(const uint4*)&wl[wbase + (K0) + wc * 8];           \
        wlr1 = *(const uint4*)&wl[wbase + (K0) + 32 + wc * 8];      \
    } while (0)

#define STORE_TILE(B)                                               \
    do {                                                            \
        u32 h0, h1, l0, l1;                                         \
        split2(xr0.x, xr0.y, h0, l0);                               \
        split2(xr0.z, xr0.w, h1, l1);                               \
        *(uint2*)&Xh[B][srow][sc * 4]      = make_uint2(h0, h1);    \
        *(uint2*)&Xl[B][srow][sc * 4]      = make_uint2(l0, l1);    \
        split2(xr1.x, xr1.y, h0, l0);                               \
        split2(xr1.z, xr1.w, h1, l1);                               \
        *(uint2*)&Xh[B][srow][32 + sc * 4] = make_uint2(h0, h1);    \
        *(uint2*)&Xl[B][srow][32 + sc * 4] = make_uint2(l0, l1);    \
        *(uint4*)&Wh[B][wrow][wc * 8]      = whr0;                  \
        *(uint4*)&Wh[B][wrow][32 + wc * 8] = whr1;                  \
        *(uint4*)&Wl[B][wrow][wc * 8]      = wlr0;                  \
        *(uint4*)&Wl[B][wrow][32 + wc * 8] = wlr1;                  \
    } while (0)

    // prologue: tile 0 -> LDS[0]
    LOAD_TILE(0);
    STORE_TILE(0);
    __syncthreads();

    for (int tile = 0; tile < NTILE; ++tile) {
        const int buf = tile & 1;
        if (tile + 1 < NTILE) LOAD_TILE((tile + 1) * KT);
        // compute on LDS[buf]
#pragma unroll
        for (int c = 0; c < 2; ++c) {
            const int ko = c * 32 + q * 8;
            v8s ah  = *(const v8s*)&Xh[buf][arow][ko];
            v8s al  = *(const v8s*)&Xl[buf][arow][ko];
            v8s bh0 = *(const v8s*)&Wh[buf][brow0][ko];
            v8s bl0 = *(const v8s*)&Wl[buf][brow0][ko];
            v8s bh1 = *(const v8s*)&Wh[buf][brow1][ko];
            v8s bl1 = *(const v8s*)&Wl[buf][brow1][ko];
            acc0 = __builtin_amdgcn_mfma_f32_16x16x32_bf16(ah, bh0, acc0, 0, 0, 0);
            acc0 = __builtin_amdgcn_mfma_f32_16x16x32_bf16(al, bh0, acc0, 0, 0, 0);
            acc0 = __builtin_amdgcn_mfma_f32_16x16x32_bf16(ah, bl0, acc0, 0, 0, 0);
            acc1 = __builtin_amdgcn_mfma_f32_16x16x32_bf16(ah, bh1, acc1, 0, 0, 0);
            acc1 = __builtin_amdgcn_mfma_f32_16x16x32_bf16(al, bh1, acc1, 0, 0, 0);
            acc1 = __builtin_amdgcn_mfma_f32_16x16x32_bf16(ah, bl1, acc1, 0, 0, 0);
        }
        if (tile + 1 < NTILE) STORE_TILE(buf ^ 1);   // write the OTHER buffer: no intra-iter race
        __syncthreads();                             // single barrier per tile
    }

    // scatter logits (D layout: col = lane&15, row = q*4 + reg)
#pragma unroll
    for (int reg = 0; reg < 4; ++reg) {
        Ls[wt * 16 + q * 4 + reg][weh * 32 + r]      = acc0[reg];
        Ls[wt * 16 + q * 4 + reg][weh * 32 + 16 + r] = acc1[reg];
    }
    __syncthreads();

    if (t < MT) {
        const int tk = t;
        float m = -3.402823466e+38f;
        for (int e = 0; e < NE; ++e) m = fmaxf(m, Ls[tk][e]);
        float s = 0.f;
        float v1 = -1.f, v2 = -1.f;
        int   i1 = 0, i2 = 0;
        for (int e = 0; e < NE; ++e) {
            const float ex = expf(Ls[tk][e] - m);
            s += ex;
            if (ex > v1)      { v2 = v1; i2 = i1; v1 = ex; i1 = e; }
            else if (ex > v2) { v2 = ex; i2 = e; }
        }
        const float s1 = v1 / s, s2 = v2 / s;
        const float ws_ = s1 + s2;
        wout[(size_t)(tok0 + tk) * 2 + 0] = s1 / ws_;
        wout[(size_t)(tok0 + tk) * 2 + 1] = s2 / ws_;
        iout[(size_t)(tok0 + tk) * 2 + 0] = (float)i1;
        iout[(size_t)(tok0 + tk) * 2 + 1] = (float)i2;
        Ssum[tk] = s;
        Smax[tk] = m;
    }
    __syncthreads();

    // coalesced scores write: 32*64 = 2048 elems / 256 threads
#pragma unroll
    for (int it = 0; it < (MT * NE) / NTHR; ++it) {
        const int f  = it * NTHR + t;
        const int tk = f >> 6, e = f & 63;
        scores[(size_t)(tok0 + tk) * NE + e] = expf(Ls[tk][e] - Smax[tk]) / Ssum[tk];
    }
}

extern "C" void kernel_launch(void* const* d_in, const int* in_sizes, int n_in,
                              void* d_out, int out_size, void* d_ws, size_t ws_size,
                              hipStream_t stream) {
    (void)in_sizes; (void)n_in; (void)out_size; (void)ws_size;
    const float* x = (const float*)d_in[0];
    const float* W = (const float*)d_in[1];
    float* out    = (float*)d_out;
    float* scores = out;
    float* wout   = scores + (size_t)TOKS * NE;
    float* iout   = wout   + (size_t)TOKS * 2;

    u16* wh = (u16*)d_ws;
    u16* wl = wh + (size_t)NE * HD;

    wsplit_kernel<<<dim3(256), dim3(256), 0, stream>>>(W, wh, wl);
    router_kernel<<<dim3(TOKS / MT), dim3(NTHR), 0, stream>>>(x, wh, wl, scores, wout, iout);
}